// Round 2
// baseline (534.551 us; speedup 1.0000x reference)
//
#include <hip/hip_runtime.h>

#define NN 50000
#define EE 800000

typedef short short8 __attribute__((ext_vector_type(8)));
typedef float f32x4 __attribute__((ext_vector_type(4)));

__device__ __forceinline__ float bf2f(unsigned short u){
  union { unsigned int i; float f; } c; c.i = ((unsigned int)u) << 16; return c.f;
}
__device__ __forceinline__ unsigned short f2bf(float f){
  union { float f; unsigned int i; } c; c.f = f;
  unsigned int i = c.i;
  unsigned int r = (i + 0x7FFFu + ((i >> 16) & 1u)) >> 16;
  return (unsigned short)r;
}

// ---- edge_index layout probe: int64 (odd int32 words all zero) vs int32 ----
__global__ void k_detect(const int* eidx, int* flag){
  int lane = threadIdx.x;              // 64 threads
  int v = eidx[2*lane + 1];            // odd positions among first 128 ints
  unsigned long long nz = __ballot(v != 0);
  if (lane == 0) *flag = (nz == 0ULL) ? 1 : 0;   // 1 => int64 layout
}

__global__ void k_count(const int* eidx, const int* flag, int* cnt){
  int e = blockIdx.x*256 + threadIdx.x;
  if (e >= EE) return;
  int m = *flag;
  int d = m ? eidx[2*(EE + e)] : eidx[EE + e];
  atomicAdd(&cnt[d], 1);
}

__global__ void k_dinv(const int* cnt, float* dinv){
  int i = blockIdx.x*256 + threadIdx.x;
  if (i < NN) dinv[i] = rsqrtf((float)(cnt[i] + 1));  // +1 self loop
}

__global__ void k_scanA(const int* cnt, int* bsum){
  __shared__ int s[512];
  int tid = threadIdx.x;
  int i = blockIdx.x*512 + tid;
  s[tid] = (i < NN) ? cnt[i] : 0;
  __syncthreads();
  for (int off = 256; off >= 1; off >>= 1){
    if (tid < off) s[tid] += s[tid + off];
    __syncthreads();
  }
  if (tid == 0) bsum[blockIdx.x] = s[0];
}

__global__ void k_scanB(int* bsum, int* row_off){
  __shared__ int s[128];
  int tid = threadIdx.x;
  int v = (tid < 98) ? bsum[tid] : 0;
  s[tid] = v;
  __syncthreads();
  for (int off = 1; off < 128; off <<= 1){
    int t = (tid >= off) ? s[tid - off] : 0;
    __syncthreads();
    s[tid] += t;
    __syncthreads();
  }
  if (tid < 98) bsum[tid] = s[tid] - v;      // exclusive block offsets
  if (tid == 0) row_off[NN] = s[127];        // total = E
}

__global__ void k_scanC(const int* cnt, const int* bsum, int* row_off, int* cursor){
  __shared__ int s[512];
  int tid = threadIdx.x;
  int i = blockIdx.x*512 + tid;
  int v = (i < NN) ? cnt[i] : 0;
  s[tid] = v;
  __syncthreads();
  for (int off = 1; off < 512; off <<= 1){
    int t = (tid >= off) ? s[tid - off] : 0;
    __syncthreads();
    s[tid] += t;
    __syncthreads();
  }
  if (i < NN){
    int val = bsum[blockIdx.x] + s[tid] - v;
    row_off[i] = val;
    cursor[i]  = val;
  }
}

__global__ void k_fill(const int* eidx, const int* flag, int* cursor, int* colv){
  int e = blockIdx.x*256 + threadIdx.x;
  if (e >= EE) return;
  int m = *flag;
  int sv = m ? eidx[2*e]        : eidx[e];
  int d  = m ? eidx[2*(EE + e)] : eidx[EE + e];
  int p = atomicAdd(&cursor[d], 1);
  colv[p] = sv;
}

// ---- B prep: f32 W -> 3-way-split bf16 B' [n][768], per k: {hi, lo, hi} ----
__global__ void k_prepB1(const float* __restrict__ W1, unsigned short* __restrict__ Bt){
  int idx = blockIdx.x*256 + threadIdx.x;   // 65536 = 256k x 256n
  int n = idx & 255, k = idx >> 8;
  float w = W1[k*256 + n];
  unsigned short hi = f2bf(w);
  unsigned short lo = f2bf(w - bf2f(hi));
  unsigned short* p = Bt + (size_t)n*768 + 3*k;
  p[0] = hi; p[1] = lo; p[2] = hi;
}
__global__ void k_prepB2(const float* __restrict__ Wmu, const float* __restrict__ Wls,
                         unsigned short* __restrict__ Bt){
  int idx = blockIdx.x*256 + threadIdx.x;
  int n = idx & 255, k = idx >> 8;
  float w = (n < 128) ? Wmu[k*128 + n] : Wls[k*128 + (n - 128)];
  unsigned short hi = f2bf(w);
  unsigned short lo = f2bf(w - bf2f(hi));
  unsigned short* p = Bt + (size_t)n*768 + 3*k;
  p[0] = hi; p[1] = lo; p[2] = hi;
}

// ---- 128x128 tile MFMA GEMM, f32 A split on the fly (K'=768), f32 C out ----
// A' per orig k: {hi, hi, lo};  B' per orig k: {hi, lo, hi}
// => sum = hiA*B + loA*hiB = A*B - loA*loB  (error ~2^-18 relative)
__global__ __launch_bounds__(256) void k_gemm(const float* __restrict__ A,
                                              const unsigned short* __restrict__ Bt,
                                              float* __restrict__ C, int M){
  __shared__ __align__(16) unsigned short sA[128*104];
  __shared__ __align__(16) unsigned short sB[128*104];
  const int tid  = threadIdx.x;
  const int wave = tid >> 6, lane = tid & 63;
  const int wm = wave >> 1, wn = wave & 1;
  const int quad = lane >> 4, l16 = lane & 15;
  const int tM = blockIdx.x, tN = blockIdx.y;

  f32x4 acc[4][4] = {};

  for (int kt = 0; kt < 8; ++kt){
    // stage A: 128 rows x 32 orig-k f32 -> 128 x 96 split bf16
    #pragma unroll
    for (int ii = 0; ii < 2; ++ii){
      int c = tid + 256*ii;           // 0..511
      int r = c >> 2;                 // 0..127
      int g = c & 3;                  // group of 8 orig k
      int arow = tM*128 + r; if (arow >= M) arow = M-1;
      const float* ap = A + (size_t)arow*256 + kt*32 + g*8;
      float4 v0 = *(const float4*)(ap);
      float4 v1 = *(const float4*)(ap + 4);
      float xs[8] = {v0.x, v0.y, v0.z, v0.w, v1.x, v1.y, v1.z, v1.w};
      __attribute__((aligned(16))) unsigned short sh[24];
      #pragma unroll
      for (int j = 0; j < 8; ++j){
        unsigned short hi = f2bf(xs[j]);
        unsigned short lo = f2bf(xs[j] - bf2f(hi));
        sh[3*j] = hi; sh[3*j+1] = hi; sh[3*j+2] = lo;
      }
      unsigned short* dp = &sA[r*104 + g*24];
      *(uint4*)(dp)      = *(const uint4*)(sh);
      *(uint4*)(dp + 8)  = *(const uint4*)(sh + 8);
      *(uint4*)(dp + 16) = *(const uint4*)(sh + 16);
    }
    // stage B: pre-split bf16 passthrough, 128 rows x 96
    #pragma unroll
    for (int ii = 0; ii < 6; ++ii){
      int c = tid + 256*ii;           // 0..1535
      int r = c / 12, ch = c % 12;
      uint4 bv = *(const uint4*)(Bt + (size_t)(tN*128 + r)*768 + kt*96 + ch*8);
      *(uint4*)(&sB[r*104 + ch*8]) = bv;
    }
    __syncthreads();
    #pragma unroll
    for (int s = 0; s < 3; ++s){
      short8 af[4], bfr[4];
      #pragma unroll
      for (int t = 0; t < 4; ++t) af[t]  = *(const short8*)(&sA[(wm*64 + t*16 + l16)*104 + s*32 + quad*8]);
      #pragma unroll
      for (int t = 0; t < 4; ++t) bfr[t] = *(const short8*)(&sB[(wn*64 + t*16 + l16)*104 + s*32 + quad*8]);
      #pragma unroll
      for (int mt = 0; mt < 4; ++mt)
        #pragma unroll
        for (int nt = 0; nt < 4; ++nt)
          acc[mt][nt] = __builtin_amdgcn_mfma_f32_16x16x32_bf16(af[mt], bfr[nt], acc[mt][nt], 0, 0, 0);
    }
    __syncthreads();
  }

  #pragma unroll
  for (int mt = 0; mt < 4; ++mt){
    #pragma unroll
    for (int r = 0; r < 4; ++r){
      int row = tM*128 + wm*64 + mt*16 + quad*4 + r;
      if (row < M){
        #pragma unroll
        for (int nt = 0; nt < 4; ++nt){
          int cc = tN*128 + wn*64 + nt*16 + l16;
          C[(size_t)row*256 + cc] = acc[mt][nt][r];
        }
      }
    }
  }
}

// ---- node-centric aggregation, one wave per node, lane owns 4 features ----
__global__ __launch_bounds__(256) void k_agg_relu(const float* __restrict__ feat,
    const float* __restrict__ dinv, const int* __restrict__ row_off, const int* __restrict__ colv,
    const float* __restrict__ b1, float* __restrict__ out){
  int i = blockIdx.x*4 + (threadIdx.x >> 6);
  if (i >= NN) return;
  int lane = threadIdx.x & 63;
  int f0 = lane*4;
  float di = dinv[i];
  float w0 = di*di;
  float4 hv = *(const float4*)(feat + (size_t)i*256 + f0);
  float a0 = hv.x*w0, a1 = hv.y*w0, a2 = hv.z*w0, a3 = hv.w*w0;
  int e0 = row_off[i], e1 = row_off[i+1];
  for (int e = e0; e < e1; ++e){
    int s = colv[e];
    float w = dinv[s]*di;
    float4 v = *(const float4*)(feat + (size_t)s*256 + f0);
    a0 += v.x*w; a1 += v.y*w; a2 += v.z*w; a3 += v.w*w;
  }
  float4 bb = *(const float4*)(b1 + f0);
  float4 o;
  o.x = fmaxf(a0 + bb.x, 0.f);
  o.y = fmaxf(a1 + bb.y, 0.f);
  o.z = fmaxf(a2 + bb.z, 0.f);
  o.w = fmaxf(a3 + bb.w, 0.f);
  *(float4*)(out + (size_t)i*256 + f0) = o;
}

__global__ __launch_bounds__(256) void k_agg_out(const float* __restrict__ feat,
    const float* __restrict__ dinv, const int* __restrict__ row_off, const int* __restrict__ colv,
    const float* __restrict__ bmu, const float* __restrict__ bls, float* __restrict__ outp){
  int i = blockIdx.x*4 + (threadIdx.x >> 6);
  if (i >= NN) return;
  int lane = threadIdx.x & 63;
  int f0 = lane*4;
  float di = dinv[i];
  float w0 = di*di;
  float4 hv = *(const float4*)(feat + (size_t)i*256 + f0);
  float a0 = hv.x*w0, a1 = hv.y*w0, a2 = hv.z*w0, a3 = hv.w*w0;
  int e0 = row_off[i], e1 = row_off[i+1];
  for (int e = e0; e < e1; ++e){
    int s = colv[e];
    float w = dinv[s]*di;
    float4 v = *(const float4*)(feat + (size_t)s*256 + f0);
    a0 += v.x*w; a1 += v.y*w; a2 += v.z*w; a3 += v.w*w;
  }
  float4 o;
  if (f0 < 128){
    float4 bb = *(const float4*)(bmu + f0);
    o.x = a0 + bb.x; o.y = a1 + bb.y; o.z = a2 + bb.z; o.w = a3 + bb.w;
    *(float4*)(outp + (size_t)i*128 + f0) = o;
  } else {
    int g = f0 - 128;
    float4 bb = *(const float4*)(bls + g);
    o.x = a0 + bb.x; o.y = a1 + bb.y; o.z = a2 + bb.z; o.w = a3 + bb.w;
    *(float4*)(outp + (size_t)NN*128 + (size_t)i*128 + g) = o;
  }
}

extern "C" void kernel_launch(void* const* d_in, const int* in_sizes, int n_in,
                              void* d_out, int out_size, void* d_ws, size_t ws_size,
                              hipStream_t stream){
  const float* x   = (const float*)d_in[0];
  const int* eidx  = (const int*)d_in[1];
  const float* W1  = (const float*)d_in[2];
  const float* b1  = (const float*)d_in[3];
  const float* Wmu = (const float*)d_in[4];
  const float* bmu = (const float*)d_in[5];
  const float* Wls = (const float*)d_in[6];
  const float* bls = (const float*)d_in[7];
  float* out = (float*)d_out;

  char* ws = (char*)d_ws;
  size_t off = 0;
  auto alloc = [&](size_t bytes)->char*{
    char* p = ws + off; off = (off + bytes + 511) & ~(size_t)511; return p;
  };
  int* cnt      = (int*)alloc(NN*4);
  float* dinv   = (float*)alloc(NN*4);
  int* row_off  = (int*)alloc((NN+1)*4);
  int* cursor   = (int*)alloc(NN*4);
  int* bsum     = (int*)alloc(128*4);
  int* flag     = (int*)alloc(4);
  int* colv     = (int*)alloc(EE*4);
  unsigned short* Bt1 = (unsigned short*)alloc((size_t)256*768*2);
  unsigned short* Bt2 = (unsigned short*)alloc((size_t)256*768*2);
  float* h   = (float*)alloc((size_t)NN*256*4);
  float* h1  = (float*)alloc((size_t)NN*256*4);
  float* z   = h;   // h dead after k_agg_relu; reuse for z

  hipMemsetAsync(cnt, 0, NN*4, stream);
  k_detect<<<1, 64, 0, stream>>>(eidx, flag);
  k_count<<<(EE+255)/256, 256, 0, stream>>>(eidx, flag, cnt);
  k_dinv<<<(NN+255)/256, 256, 0, stream>>>(cnt, dinv);
  k_scanA<<<98, 512, 0, stream>>>(cnt, bsum);
  k_scanB<<<1, 128, 0, stream>>>(bsum, row_off);
  k_scanC<<<98, 512, 0, stream>>>(cnt, bsum, row_off, cursor);
  k_fill<<<(EE+255)/256, 256, 0, stream>>>(eidx, flag, cursor, colv);
  k_prepB1<<<256, 256, 0, stream>>>(W1, Bt1);
  k_prepB2<<<256, 256, 0, stream>>>(Wmu, Wls, Bt2);
  k_gemm<<<dim3(391, 2), 256, 0, stream>>>(x, Bt1, h, NN);
  k_agg_relu<<<12500, 256, 0, stream>>>(h, dinv, row_off, colv, b1, h1);
  k_gemm<<<dim3(391, 2), 256, 0, stream>>>(h1, Bt2, z, NN);
  k_agg_out<<<12500, 256, 0, stream>>>(z, dinv, row_off, colv, bmu, bls, out);
}